// Round 5
// baseline (291.676 us; speedup 1.0000x reference)
//
#include <hip/hip_runtime.h>
#include <math.h>

#define HID 256
#define SEQ 512

typedef float v4f __attribute__((ext_vector_type(4)));

// ---------------------------------------------------------------------------
// Phase 1: inp[t][i] = b[i] + sum_j emb[idx[t]][j] * W[i][HID + j]
// One block per timestep t (512 blocks), 256 threads (one per output i).
// ---------------------------------------------------------------------------
__global__ __launch_bounds__(256) void qrnn_phase1(
    const int* __restrict__ idx, const float* __restrict__ emb,
    const float* __restrict__ W, const float* __restrict__ b,
    float* __restrict__ inp)
{
    const int t = blockIdx.x;
    const int i = threadIdx.x;
    __shared__ float xs[HID];
    const size_t row = (size_t)idx[t];
    xs[i] = emb[row * HID + i];
    __syncthreads();

    const float* wr = W + (size_t)i * (2 * HID) + HID;  // Wx row i
    float acc = b[i];
#pragma unroll
    for (int k = 0; k < HID / 4; ++k) {
        const float4 w4 = *reinterpret_cast<const float4*>(wr + k * 4);
        const float4 x4 = *reinterpret_cast<const float4*>(&xs[k * 4]);
        acc = fmaf(w4.x, x4.x, acc);
        acc = fmaf(w4.y, x4.y, acc);
        acc = fmaf(w4.z, x4.z, acc);
        acc = fmaf(w4.w, x4.w, acc);
    }
    inp[t * HID + i] = acc;
}

// DPP move from another lane (VALU pipe, no LDS).
// DIRECTION CONVENTION (GCN/CDNA): row_shr:n / row_ror:n -> lane i READS
// lane (i-n)&15 (data moves toward higher lanes). Verified by the canonical
// DPP prefix-scan idiom (row_shr:1 fetches the lower lane). Round-4 bug:
// assumed (i+n)&15 -> stage-4 lanes summed the wrong row half.
// CTRLs: 0xB1 quad_perm(1,0,3,2)=xor1 (self-inverse);
//        0x4E quad_perm(2,3,0,1)=xor2 (self-inverse);
//        0x128 ROW_ROR:8 = lane^8 (self-inverse);
//        0x124 ROW_ROR:4  -> src (i-4)&15  (correct partner for lanes i&4==1);
//        0x12C ROW_ROR:12 -> src (i+4)&15  (correct partner for lanes i&4==0).
template <int CTRL>
__device__ __forceinline__ float dpp_mov(float v)
{
    return __int_as_float(
        __builtin_amdgcn_update_dpp(0, __float_as_int(v), CTRL, 0xF, 0xF, true));
}

// Pin a row of 4 v4f into VGPRs (anti-rematerialization).
#define PIN4(a) asm volatile("" : "+v"(a[0]), "+v"(a[1]), "+v"(a[2]), "+v"(a[3]))

// ---------------------------------------------------------------------------
// Phase 2: sequential scan, single block of 512 threads (8 waves, 2/SIMD).
// Groups of 16 lanes (= one DPP row): r = tid&15, g = tid>>4 (32 groups).
// Group g owns rows [8g, 8g+8); lane r owns cols [16r, 16r+16).
// Weight tile: 8 rows x 16 cols = 128 VGPRs/thread.
// amdgpu_waves_per_eu(2,2): pin occupancy to exactly 2 waves/EU (256-reg
// budget) so regalloc doesn't offload the weight tile into AGPRs (round-3:
// VGPR_Count=84 -> weights in AGPRs, v_accvgpr_read per FMA operand).
// h double-buffered in LDS, word-swizzle sw(w) = w ^ (((w>>5)&7)<<2).
// Reduction: DPP reduce-scatter over lane bits {0,1,3} (rows 8->4->2->1),
// then one butterfly over lane bit2 -> lane holds full sum of its row
// m_r = (r&3)|((r>>1)&4); lanes with r&4==0 write.
// ---------------------------------------------------------------------------
__global__ void __launch_bounds__(512)
__attribute__((amdgpu_waves_per_eu(2, 2)))
qrnn_phase2(const float* __restrict__ W, const float* __restrict__ inp,
            float* __restrict__ out)
{
    const int tid = threadIdx.x;
    const int r = tid & 15;
    const int g = tid >> 4;                 // [0, 32)
    const bool b0 = (r & 1) != 0;
    const bool b1 = (r & 2) != 0;
    const bool b2 = (r & 4) != 0;
    const bool b3 = (r & 8) != 0;
    const int m_r = (r & 3) | ((r >> 1) & 4);   // this lane's output row-in-group
    const int i_out = 8 * g + m_r;

    __shared__ float hbuf[2][HID];
    if (tid < HID) hbuf[0][tid] = 0.0f;

    // Weight tile: wv[m][k] = W[(8g+m)][16r + 4k .. +3]  (Wh part, cols<HID)
    v4f wv[8][4];
#pragma unroll
    for (int m = 0; m < 8; ++m) {
        const float* wrow = W + (size_t)(8 * g + m) * (2 * HID) + r * 16;
#pragma unroll
        for (int k = 0; k < 4; ++k)
            wv[m][k] = *reinterpret_cast<const v4f*>(wrow + k * 4);
        PIN4(wv[m]);
    }

    // Loop-invariant swizzled word offsets
    int rdoff[4];
#pragma unroll
    for (int k = 0; k < 4; ++k) {
        const int w = 16 * r + 4 * k;
        rdoff[k] = w ^ (((w >> 5) & 7) << 2);
    }
    const int wroff = i_out ^ (((i_out >> 5) & 7) << 2);

    float ip = inp[i_out];  // inp[0][i_out]
    float h = 0.0f;
    __syncthreads();

    auto step = [&](const float* __restrict__ src, float* __restrict__ dst,
                    int tnext) {
        // This lane's 16 h values: 4 swizzled float4 reads (2-way max -> free)
        v4f h4[4];
#pragma unroll
        for (int k = 0; k < 4; ++k)
            h4[k] = *reinterpret_cast<const v4f*>(src + rdoff[k]);

        // Prefetch next step's inp (branchless; latency hidden under FMAs)
        float ip_next = inp[(tnext & (SEQ - 1)) * HID + i_out];

        // 8 partial dots (16 terms each) -> 128 FMAs, 8 independent chains
        float acc[8];
#pragma unroll
        for (int m = 0; m < 8; ++m) {
            float a = 0.0f;
#pragma unroll
            for (int k = 0; k < 4; ++k) {
                a = fmaf(wv[m][k].x, h4[k].x, a);
                a = fmaf(wv[m][k].y, h4[k].y, a);
                a = fmaf(wv[m][k].z, h4[k].z, a);
                a = fmaf(wv[m][k].w, h4[k].w, a);
            }
            acc[m] = a;
        }

        // --- DPP reduce-scatter across the 16-lane group ---
        // Stage 1: lane bit0 <-> row bit0 (8 -> 4). Keep rows with bit0==b0.
        float q[4];
#pragma unroll
        for (int j = 0; j < 4; ++j) {
            float give = b0 ? acc[2 * j] : acc[2 * j + 1];
            float keep = b0 ? acc[2 * j + 1] : acc[2 * j];
            q[j] = keep + dpp_mov<0xB1>(give);
        }
        // Stage 2: lane bit1 <-> row bit1 (4 -> 2).
        float s2[2];
#pragma unroll
        for (int k2 = 0; k2 < 2; ++k2) {
            float give = b1 ? q[2 * k2] : q[2 * k2 + 1];
            float keep = b1 ? q[2 * k2 + 1] : q[2 * k2];
            s2[k2] = keep + dpp_mov<0x4E>(give);
        }
        // Stage 3: lane bit3 <-> row bit2 (2 -> 1). lane^8 = ROW_ROR:8.
        float give3 = b3 ? s2[0] : s2[1];
        float keep3 = b3 ? s2[1] : s2[0];
        float ssum = keep3 + dpp_mov<0x128>(give3);
        // Stage 4: butterfly over lane bit2. Partner is lane r^4.
        // ROR:n -> src (i-n)&15, so b2==0 lanes (need src r+4) use ROR:12,
        // b2==1 lanes (need src r-4) use ROR:4.  [round-4 bug: was swapped]
        float a4  = dpp_mov<0x124>(ssum);   // src (i-4)&15
        float a12 = dpp_mov<0x12C>(ssum);   // src (i+4)&15
        float total = ssum + (b2 ? a4 : a12);

        float d = total + ip;
        // tanh(d) = 1 - 2/(exp(2d)+1)
        float e = __expf(2.0f * d);
        h = 1.0f - 2.0f / (e + 1.0f);

        // Writer lanes (b2==0) store h_new[i_out]; per wave the 32 swizzled
        // words cover all 32 banks -> conflict-free.
        if (!b2) dst[wroff] = h;

        ip = ip_next;
        __syncthreads();
    };

#pragma unroll 1
    for (int t = 0; t < SEQ; t += 2) {
        step(&hbuf[0][0], &hbuf[1][0], t + 1);
        step(&hbuf[1][0], &hbuf[0][0], t + 2);
    }

    if (!b2) out[i_out] = h;
}

extern "C" void kernel_launch(void* const* d_in, const int* in_sizes, int n_in,
                              void* d_out, int out_size, void* d_ws, size_t ws_size,
                              hipStream_t stream)
{
    const int*   idx = (const int*)d_in[0];
    const float* emb = (const float*)d_in[1];
    const float* W   = (const float*)d_in[2];
    const float* b   = (const float*)d_in[3];
    float* out = (float*)d_out;
    float* inp = (float*)d_ws;  // SEQ*HID*4 = 512 KB scratch

    qrnn_phase1<<<SEQ, HID, 0, stream>>>(idx, emb, W, b, inp);
    qrnn_phase2<<<1, 512, 0, stream>>>(W, inp, out);
}